// Round 10
// baseline (127.017 us; speedup 1.0000x reference)
//
#include <hip/hip_runtime.h>
#include <hip/hip_bf16.h>

// Problem constants
#define BDIM 8
#define HDIM 64
#define WDIM 64
#define CDIM 192
#define CIDIM 384
#define MTOK (BDIM * HDIM * WDIM)   // 32768 tokens

using bf16 = __hip_bfloat16;
typedef __attribute__((ext_vector_type(8))) short short8;   // 8 bf16 (4 VGPRs)
typedef __attribute__((ext_vector_type(4))) float f32x4;

__device__ __forceinline__ float silu_f(float v) { return v / (1.0f + __expf(-v)); }
__device__ __forceinline__ float bf2f(short s) {
    union { unsigned u; float f; } x; x.u = ((unsigned)(unsigned short)s) << 16; return x.f;
}

// async global->LDS, 16B per lane. LDS dest must be WAVE-UNIFORM base (+lane*16);
// the GLOBAL source address is per-lane.
__device__ __forceinline__ void gload_lds16(const bf16* g, bf16* l) {
    __builtin_amdgcn_global_load_lds(
        (const __attribute__((address_space(1))) void*)g,
        (__attribute__((address_space(3))) void*)l, 16, 0, 0);
}

// ---------------------------------------------------------------------------
// Full-K GEMM for K=192 (G1, G4): C[M,N] = A[M,192] @ B[192,N], B given
// TRANSPOSED [N,192]. BM=BN=64, ALL of K staged once in LDS (48 KB):
// one issue -> one drain -> 24 MFMA/wave -> LDS-transposed VECTOR store.
// Grid 1D, XCD-bijective swizzle: bid%8 == by%8 -> A panel pinned to one XCD L2.
// Staging swizzle: physical 16B slot p of row holds logical slot p^(row&7).
// Epilogue: acc -> (transform) -> LDS [64][8 chunks] with chunk^=(row&7)
// swizzle -> ds_read_b128 -> global_store_dwordx4 (16B/lane, 128B/8 lanes).
// EPI 0: split-store c<384 -> outB (x1), else outB2 = 4*silu(v)      [G1]
// EPI 2: silu(v+bias) -> outB bf16                                    [G4]
// ---------------------------------------------------------------------------
template <int EPI>
__launch_bounds__(256, 3)
__global__ void gemm_k192(const bf16* __restrict__ A, const bf16* __restrict__ BT,
                          const float* __restrict__ bias,
                          bf16* __restrict__ outB, bf16* __restrict__ outB2,
                          int N, int NX)
{
    __shared__ bf16 As[64 * 192];   // 24 KB
    __shared__ bf16 Bs[64 * 192];   // 24 KB

    const int bid = blockIdx.x;
    const int c8  = bid & 7;
    const int kk_ = bid >> 3;
    const int bx  = kk_ % NX;
    const int by  = (kk_ / NX) * 8 + c8;   // y%8 == bid%8 -> XCD-pinned panel
    const int m0  = by * 64;
    const int n0  = bx * 64;

    const int tid  = threadIdx.x;
    const int lane = tid & 63;
    const int wv   = tid >> 6;
    const int wm   = wv >> 1;
    const int wn   = wv & 1;

    // --- stage: 24 chunks (1KB each) per matrix, 6 per wave ---
    #pragma unroll
    for (int i = 0; i < 6; ++i) {
        const int ci   = wv * 6 + i;
        const int c    = ci * 64 + lane;      // 16B-chunk index 0..1535
        const int row  = c / 24;
        const int slot = c - row * 24;        // physical slot 0..23
        const int lsl  = slot ^ (row & 7);    // logical slot fetched here
        gload_lds16(A  + (size_t)(m0 + row) * 192 + lsl * 8, &As[ci * 512]);
        gload_lds16(BT + (size_t)(n0 + row) * 192 + lsl * 8, &Bs[ci * 512]);
    }
    __syncthreads();   // single drain

    // --- compute: wave tile 32x32, 6 k-steps, 24 MFMA ---
    f32x4 acc[2][2] = {};
    #pragma unroll
    for (int ks = 0; ks < 6; ++ks) {
        const int t = ks * 4 + (lane >> 4);
        short8 af[2], bfr[2];
        #pragma unroll
        for (int mi = 0; mi < 2; ++mi) {
            const int m = wm * 32 + mi * 16 + (lane & 15);
            af[mi] = *reinterpret_cast<const short8*>(&As[m * 192 + ((t ^ (m & 7)) << 3)]);
        }
        #pragma unroll
        for (int ni = 0; ni < 2; ++ni) {
            const int n = wn * 32 + ni * 16 + (lane & 15);
            bfr[ni] = *reinterpret_cast<const short8*>(&Bs[n * 192 + ((t ^ (n & 7)) << 3)]);
        }
        #pragma unroll
        for (int mi = 0; mi < 2; ++mi)
            #pragma unroll
            for (int ni = 0; ni < 2; ++ni)
                acc[mi][ni] = __builtin_amdgcn_mfma_f32_16x16x32_bf16(
                    af[mi], bfr[ni], acc[mi][ni], 0, 0, 0);
    }

    // --- epilogue v2: transform -> LDS (8 KB, reuse As) -> vector store ---
    const bool isZ = (EPI == 0) && (n0 >= CIDIM);   // block-uniform for G1
    bf16* lc = As;   // [64 rows][64 cols], 16B chunks XOR-swizzled by row

    __syncthreads();   // all LDS reads done before overwrite
    {
        const int colb = wn * 32 + (lane & 15);          // tile-local col
        const int rowb = wm * 32 + (lane >> 4) * 4;      // tile-local row base
        #pragma unroll
        for (int mi = 0; mi < 2; ++mi) {
            #pragma unroll
            for (int ni = 0; ni < 2; ++ni) {
                const int c = colb + ni * 16;
                #pragma unroll
                for (int j = 0; j < 4; ++j) {
                    const int r = rowb + mi * 16 + j;
                    float v = acc[mi][ni][j];
                    if constexpr (EPI == 0) {
                        if (isZ) v = 4.0f * silu_f(v);
                    } else {
                        v = silu_f(v + bias[n0 + c]);
                    }
                    const int phys = ((c >> 3) ^ (r & 7)) * 8 + (c & 7);
                    lc[r * 64 + phys] = __float2bfloat16(v);
                }
            }
        }
    }
    __syncthreads();

    {
        bf16* dst = (EPI == 0 && isZ) ? outB2 : outB;
        const int ncol0  = (EPI == 0) ? (isZ ? n0 - CIDIM : n0) : n0;
        const int stride = (EPI == 0) ? CIDIM : N;
        #pragma unroll
        for (int s = 0; s < 2; ++s) {
            const int cid  = s * 256 + tid;        // chunk id 0..511
            const int row  = cid >> 3;
            const int ch   = cid & 7;
            const short8 v8 = *reinterpret_cast<const short8*>(
                &lc[row * 64 + (ch ^ (row & 7)) * 8]);
            *reinterpret_cast<short8*>(
                &dst[(size_t)(m0 + row) * stride + ncol0 + ch * 8]) = v8;
        }
    }
}

// ---------------------------------------------------------------------------
// Loop GEMM (K=384/768): BM=128, BN=64, BK=64. 4 waves 2x2; wave 64x32.
// 1D grid + XCD-bijective swizzle (y%8 == bid%8).
// EPI 1: +residF(fp32) -> outB bf16 only                              [G3]
// EPI 3: v + bias + bf2f(residB) -> outF fp32                         [G5]
// ---------------------------------------------------------------------------
template <int EPI>
__launch_bounds__(256, 4)
__global__ void gemm_mfma(const bf16* __restrict__ A, const bf16* __restrict__ BT,
                          const float* __restrict__ bias,
                          const float* __restrict__ residF,
                          const bf16* __restrict__ residB,
                          float* __restrict__ outF, bf16* __restrict__ outB,
                          int M, int N, int K, int NX)
{
    __shared__ bf16 As[128 * 64];
    __shared__ bf16 Bs[64 * 64];

    const int bid = blockIdx.x;
    const int c8  = bid & 7;
    const int kq  = bid >> 3;
    const int bx  = kq % NX;
    const int by  = (kq / NX) * 8 + c8;
    const int m0  = by * 128;
    const int n0  = bx * 64;

    const int tid  = threadIdx.x;
    const int lane = tid & 63;
    const int wv   = tid >> 6;
    const int wm   = wv >> 1;
    const int wn   = wv & 1;

    const int srow  = lane >> 3;
    const int sslot = lane & 7;

    f32x4 acc[4][2] = {};

    for (int k0 = 0; k0 < K; k0 += 64) {
        #pragma unroll
        for (int i = 0; i < 4; ++i) {
            const int rb = wv * 32 + i * 8;
            const int r  = rb + srow;
            gload_lds16(A + (size_t)(m0 + r) * K + k0 + ((sslot ^ (r & 7)) << 3),
                        &As[rb * 64]);
        }
        #pragma unroll
        for (int i = 0; i < 2; ++i) {
            const int rb = wv * 16 + i * 8;
            const int r  = rb + srow;
            gload_lds16(BT + (size_t)(n0 + r) * K + k0 + ((sslot ^ (r & 7)) << 3),
                        &Bs[rb * 64]);
        }
        __syncthreads();

        #pragma unroll
        for (int kk = 0; kk < 2; ++kk) {
            const int t = kk * 4 + (lane >> 4);
            short8 af[4], bfr[2];
            #pragma unroll
            for (int mi = 0; mi < 4; ++mi) {
                const int m = wm * 64 + mi * 16 + (lane & 15);
                af[mi] = *reinterpret_cast<const short8*>(&As[m * 64 + ((t ^ (m & 7)) << 3)]);
            }
            #pragma unroll
            for (int ni = 0; ni < 2; ++ni) {
                const int n = wn * 32 + ni * 16 + (lane & 15);
                bfr[ni] = *reinterpret_cast<const short8*>(&Bs[n * 64 + ((t ^ (n & 7)) << 3)]);
            }
            #pragma unroll
            for (int mi = 0; mi < 4; ++mi)
                #pragma unroll
                for (int ni = 0; ni < 2; ++ni)
                    acc[mi][ni] = __builtin_amdgcn_mfma_f32_16x16x32_bf16(
                        af[mi], bfr[ni], acc[mi][ni], 0, 0, 0);
        }
        __syncthreads();
    }

    const int colb = n0 + wn * 32 + (lane & 15);
    const int rowb = m0 + wm * 64 + (lane >> 4) * 4;
    #pragma unroll
    for (int mi = 0; mi < 4; ++mi) {
        #pragma unroll
        for (int ni = 0; ni < 2; ++ni) {
            const int c = colb + ni * 16;
            #pragma unroll
            for (int j = 0; j < 4; ++j) {
                const int row = rowb + mi * 16 + j;
                const size_t off = (size_t)row * N + c;
                const float v = acc[mi][ni][j];
                if constexpr (EPI == 1) {
                    outB[off] = __float2bfloat16(v + residF[off]);
                } else {
                    outF[off] = v + bias[c] + bf2f(*(const short*)&residB[off]);
                }
            }
        }
    }
}

// ---------------------------------------------------------------------------
// Depthwise 3x3 conv + bias + silu, gated. Dense streams:
// x1 [M,384] bf16, sz [M,384] bf16 (= 4*silu(z)). Item f = m*48 + cg.
// y[m,c] = silu(conv(x1)+b) * sz.  Grid: 6144 blocks x 256 thr, XCD-swizzled.
// ---------------------------------------------------------------------------
__launch_bounds__(256)
__global__ void dwconv_gate_v6(const bf16* __restrict__ x1, const bf16* __restrict__ sz,
                               const float* __restrict__ wT, const float* __restrict__ conv_b,
                               bf16* __restrict__ y)
{
    const int bid = blockIdx.x;
    const int swz = (bid & 7) * ((int)gridDim.x >> 3) + (bid >> 3);   // bijective (6144 % 8 == 0)
    const int f   = swz * 256 + threadIdx.x;
    const int m   = f / 48;
    const int cg  = f - m * 48;
    const int c0  = cg * 8;
    const int h   = (m >> 6) & 63;
    const int w   = m & 63;

    float acc[8];
    {
        const f32x4 ba = *reinterpret_cast<const f32x4*>(&conv_b[c0]);
        const f32x4 bb = *reinterpret_cast<const f32x4*>(&conv_b[c0 + 4]);
        acc[0] = ba[0]; acc[1] = ba[1]; acc[2] = ba[2]; acc[3] = ba[3];
        acc[4] = bb[0]; acc[5] = bb[1]; acc[6] = bb[2]; acc[7] = bb[3];
    }

    #pragma unroll
    for (int r = 0; r < 3; ++r) {
        const int hh = h + r - 1;
        if (hh < 0 || hh >= HDIM) continue;
        #pragma unroll
        for (int dw = 0; dw < 3; ++dw) {
            const int ww = w + dw - 1;
            if (ww < 0 || ww >= WDIM) continue;
            const int mm  = m + (r - 1) * WDIM + (dw - 1);
            const int tap = r * 3 + dw;
            const short8 t = *reinterpret_cast<const short8*>(&x1[(size_t)mm * CIDIM + c0]);
            const f32x4 wa = *reinterpret_cast<const f32x4*>(&wT[tap * CIDIM + c0]);
            const f32x4 wb = *reinterpret_cast<const f32x4*>(&wT[tap * CIDIM + c0 + 4]);
            acc[0] += bf2f(t[0]) * wa[0]; acc[1] += bf2f(t[1]) * wa[1];
            acc[2] += bf2f(t[2]) * wa[2]; acc[3] += bf2f(t[3]) * wa[3];
            acc[4] += bf2f(t[4]) * wb[0]; acc[5] += bf2f(t[5]) * wb[1];
            acc[6] += bf2f(t[6]) * wb[2]; acc[7] += bf2f(t[7]) * wb[3];
        }
    }

    const short8 g = *reinterpret_cast<const short8*>(&sz[(size_t)m * CIDIM + c0]);
    bf16 tmp[8];
    #pragma unroll
    for (int j = 0; j < 8; ++j)
        tmp[j] = __float2bfloat16(silu_f(acc[j]) * bf2f(g[j]));
    *reinterpret_cast<short8*>(&y[(size_t)m * CIDIM + c0]) =
        *reinterpret_cast<const short8*>(tmp);
}

// ---------------------------------------------------------------------------
// ALL preprocessing in ONE launch: x fp32->bf16 (4/thread) + 4 weight
// transposes to bf16 [N,K] + conv_w transpose, flat-index dispatched.
// ---------------------------------------------------------------------------
#define SZ_WIN  (192 * 768)
#define SZ_WOUT (384 * 192)
#define SZ_WM1  (192 * 768)
#define SZ_WM2  (768 * 192)
#define SZ_CW   (CIDIM * 9)
#define XCVT    (MTOK * CDIM / 4)
#define SZ_ALL  (XCVT + SZ_WIN + SZ_WOUT + SZ_WM1 + SZ_WM2 + SZ_CW)

__launch_bounds__(256)
__global__ void prep_all(const float* __restrict__ x, const float* __restrict__ Win,
                         const float* __restrict__ Wout, const float* __restrict__ Wm1,
                         const float* __restrict__ Wm2, const float* __restrict__ convw,
                         bf16* __restrict__ xb, bf16* __restrict__ WinT,
                         bf16* __restrict__ WoutT, bf16* __restrict__ Wm1T,
                         bf16* __restrict__ Wm2T, float* __restrict__ wTc)
{
    int idx = blockIdx.x * 256 + threadIdx.x;
    if (idx < XCVT) {
        const int i = idx * 4;
        const float4 v = *reinterpret_cast<const float4*>(&x[i]);
        xb[i + 0] = __float2bfloat16(v.x);
        xb[i + 1] = __float2bfloat16(v.y);
        xb[i + 2] = __float2bfloat16(v.z);
        xb[i + 3] = __float2bfloat16(v.w);
        return;
    }
    idx -= XCVT;
    if (idx < SZ_WIN) {
        const int r = idx / 768, c = idx % 768;
        WinT[(size_t)c * 192 + r] = __float2bfloat16(Win[idx]);
        return;
    }
    idx -= SZ_WIN;
    if (idx < SZ_WOUT) {
        const int r = idx / 192, c = idx % 192;
        WoutT[(size_t)c * 384 + r] = __float2bfloat16(Wout[idx]);
        return;
    }
    idx -= SZ_WOUT;
    if (idx < SZ_WM1) {
        const int r = idx / 768, c = idx % 768;
        Wm1T[(size_t)c * 192 + r] = __float2bfloat16(Wm1[idx]);
        return;
    }
    idx -= SZ_WM1;
    if (idx < SZ_WM2) {
        const int r = idx / 192, c = idx % 192;
        Wm2T[(size_t)c * 768 + r] = __float2bfloat16(Wm2[idx]);
        return;
    }
    idx -= SZ_WM2;
    if (idx < SZ_CW) {
        const int ci = idx / 9, t = idx % 9;
        wTc[t * CIDIM + ci] = convw[idx];
    }
}

// ---------------------------------------------------------------------------
extern "C" void kernel_launch(void* const* d_in, const int* in_sizes, int n_in,
                              void* d_out, int out_size, void* d_ws, size_t ws_size,
                              hipStream_t stream)
{
    const float* x      = (const float*)d_in[0];
    const float* Win    = (const float*)d_in[1];
    const float* conv_w = (const float*)d_in[2];
    const float* conv_b = (const float*)d_in[3];
    const float* Wout   = (const float*)d_in[4];
    const float* Wm1    = (const float*)d_in[5];
    const float* bm1    = (const float*)d_in[6];
    const float* Wm2    = (const float*)d_in[7];
    const float* bm2    = (const float*)d_in[8];
    float* out = (float*)d_out;

    char* ws = (char*)d_ws;
    size_t o = 0;
    bf16*  xb    = (bf16*)(ws + o); o += (size_t)MTOK * CDIM * 2;
    bf16*  WinT  = (bf16*)(ws + o); o += (size_t)768 * 192 * 2;
    bf16*  WoutT = (bf16*)(ws + o); o += (size_t)192 * 384 * 2;
    bf16*  Wm1T  = (bf16*)(ws + o); o += (size_t)768 * 192 * 2;
    bf16*  Wm2T  = (bf16*)(ws + o); o += (size_t)192 * 768 * 2;
    float* wTc   = (float*)(ws + o); o += (size_t)9 * CIDIM * 4;
    bf16*  ws_x1 = (bf16*)(ws + o); o += (size_t)MTOK * CIDIM * 2;   // dense x1 [M,384]
    bf16*  ws_sz = (bf16*)(ws + o); o += (size_t)MTOK * CIDIM * 2;   // dense 4*silu(z)
    bf16*  ws_y  = (bf16*)(ws + o); o += (size_t)MTOK * CIDIM * 2;
    bf16*  ws_ob = (bf16*)(ws + o); o += (size_t)MTOK * CDIM * 2;    // out bf16 [M,192]
    bf16*  ws_h  = ws_x1;   // GEMM4 output [M,768] reuses x1+sz region (dead by then)

    // 0) all conversions/transposes in one launch
    prep_all<<<dim3((SZ_ALL + 255) / 256), dim3(256), 0, stream>>>(
        x, Win, Wout, Wm1, Wm2, conv_w, xb, WinT, WoutT, Wm1T, Wm2T, wTc);

    // 1) xz = x @ Win  [M,768], K=192 -> split dense x1 / sz(=4*silu(z))
    //    full-K single-stage, 64x64 tiles, XCD-pinned A panels, vector stores
    gemm_k192<0><<<dim3(12 * 512), dim3(256), 0, stream>>>(
        xb, WinT, nullptr, ws_x1, ws_sz, 768, 12);

    // 2) y = silu(dwconv(x1)+b) * sz -> bf16
    dwconv_gate_v6<<<dim3(MTOK * 48 / 256), dim3(256), 0, stream>>>(
        ws_x1, ws_sz, wTc, conv_b, ws_y);

    // 3) out = x + y @ Wout   [M,192], K=384 -> bf16 ob ONLY
    gemm_mfma<1><<<dim3(3 * 256), dim3(256), 0, stream>>>(
        ws_y, WoutT, nullptr, x, nullptr, nullptr, ws_ob, MTOK, CDIM, CIDIM, 3);

    // 4) h = silu(out @ Wm1 + bm1)   [M,768], K=192 -> bf16 (full-K kernel)
    gemm_k192<2><<<dim3(12 * 512), dim3(256), 0, stream>>>(
        ws_ob, Wm1T, bm1, ws_h, nullptr, 768, 12);

    // 5) final = bf16(out) + h @ Wm2 + bm2   [M,192], K=768 -> fp32
    gemm_mfma<3><<<dim3(3 * 256), dim3(256), 0, stream>>>(
        ws_h, Wm2T, bm2, nullptr, ws_ob, out, nullptr, MTOK, CDIM, 768, 3);
}

// Round 11
// 121.823 us; speedup vs baseline: 1.0426x; 1.0426x over previous
//
#include <hip/hip_runtime.h>
#include <hip/hip_bf16.h>

// Problem constants
#define BDIM 8
#define HDIM 64
#define WDIM 64
#define CDIM 192
#define CIDIM 384
#define MTOK (BDIM * HDIM * WDIM)   // 32768 tokens

using bf16 = __hip_bfloat16;
typedef __attribute__((ext_vector_type(8))) short short8;   // 8 bf16 (4 VGPRs)
typedef __attribute__((ext_vector_type(4))) float f32x4;

__device__ __forceinline__ float silu_f(float v) { return v / (1.0f + __expf(-v)); }
__device__ __forceinline__ float bf2f(short s) {
    union { unsigned u; float f; } x; x.u = ((unsigned)(unsigned short)s) << 16; return x.f;
}

// async global->LDS, 16B per lane. LDS dest must be WAVE-UNIFORM base (+lane*16);
// the GLOBAL source address is per-lane.
__device__ __forceinline__ void gload_lds16(const bf16* g, bf16* l) {
    __builtin_amdgcn_global_load_lds(
        (const __attribute__((address_space(1))) void*)g,
        (__attribute__((address_space(3))) void*)l, 16, 0, 0);
}

// ---------------------------------------------------------------------------
// PERSISTENT full-K GEMM for K=192 (G1, G4): C[M,N] = A[M,192] @ B[192,N],
// B given TRANSPOSED [N,192]. Block owns ONE 64-col n-tile + a stripe of
// 12-13 m-tiles (mt = s, s+40, ...). B staged ONCE (24 KB); A double-buffered
// (2x24 KB): per iter {stage A[t+1] -> buf^1; compute buf; store; barrier}.
// Staging (row,slot) offsets are m-invariant -> computed once in prologue.
// Grid 480 = 12 n x 40 stripes; 40%8==0 -> bid%8 = s%8: all 12 consumers of
// an A panel land on one XCD's L2. LDS 72 KB -> 2 blocks/CU.
// Row = 24 x 16B slots; physical slot p holds logical p^(row&7) (both-sides).
// EPI 0: split-store c<384 -> outB (x1), else outB2 = 4*silu(v)      [G1]
// EPI 2: silu(v+bias) -> outB bf16, stride 768                        [G4]
// ---------------------------------------------------------------------------
#define NSTRIPE 40
template <int EPI>
__launch_bounds__(256, 2)
__global__ void gemm_k192_p(const bf16* __restrict__ A, const bf16* __restrict__ BT,
                            const float* __restrict__ bias,
                            bf16* __restrict__ outB, bf16* __restrict__ outB2)
{
    __shared__ bf16 As[2][64 * 192];   // 48 KB (double-buffered A)
    __shared__ bf16 Bs[64 * 192];      // 24 KB (resident B n-tile)

    const int bid = blockIdx.x;
    const int n   = bid / NSTRIPE;       // 0..11
    const int s   = bid % NSTRIPE;       // stripe; XCD = s%8 for all n
    const int n0  = n * 64;

    const int tid  = threadIdx.x;
    const int lane = tid & 63;
    const int wv   = tid >> 6;
    const int wm   = wv >> 1;
    const int wn   = wv & 1;

    // --- prologue: m-invariant staging offsets (6 chunks per wave) ---
    int soff[6];
    #pragma unroll
    for (int i = 0; i < 6; ++i) {
        const int ci   = wv * 6 + i;
        const int c    = ci * 64 + lane;      // 16B-chunk 0..1535
        const int row  = c / 24;
        const int slot = c - row * 24;        // physical slot
        const int lsl  = slot ^ (row & 7);    // logical slot fetched here
        soff[i] = row * 192 + lsl * 8;
    }

    // stage B once
    #pragma unroll
    for (int i = 0; i < 6; ++i)
        gload_lds16(BT + (size_t)n0 * 192 + soff[i], &Bs[(wv * 6 + i) * 512]);

    // stage first A tile into buf 0
    #pragma unroll
    for (int i = 0; i < 6; ++i)
        gload_lds16(A + (size_t)(s * 64) * 192 + soff[i], &As[0][(wv * 6 + i) * 512]);
    __syncthreads();

    // per-thread read/store invariants
    const int mloc[2] = { wm * 32 + (lane & 15), wm * 32 + 16 + (lane & 15) };
    const int nloc[2] = { wn * 32 + (lane & 15), wn * 32 + 16 + (lane & 15) };
    const bool isZ = (EPI == 0) && (n0 >= CIDIM);
    bf16* dst        = (EPI == 0) ? (isZ ? outB2 : outB) : outB;
    const int stride = (EPI == 0) ? CIDIM : 768;
    const int col0   = (EPI == 0) ? (isZ ? n0 - CIDIM : n0) : n0;

    int cur = 0;
    for (int mt = s; mt < 512; mt += NSTRIPE) {
        // 2-phase: issue next A stage before computing current
        const int nmt = mt + NSTRIPE;
        if (nmt < 512) {
            const bf16* a1 = A + (size_t)(nmt * 64) * 192;
            bf16* db = As[cur ^ 1];
            #pragma unroll
            for (int i = 0; i < 6; ++i)
                gload_lds16(a1 + soff[i], &db[(wv * 6 + i) * 512]);
        }

        // compute: wave tile 32x32, 6 k-steps, 24 MFMA
        const bf16* la = As[cur];
        f32x4 acc[2][2] = {};
        #pragma unroll
        for (int ks = 0; ks < 6; ++ks) {
            const int t = ks * 4 + (lane >> 4);
            short8 af[2], bfr[2];
            #pragma unroll
            for (int mi = 0; mi < 2; ++mi) {
                const int m = mloc[mi];
                af[mi] = *reinterpret_cast<const short8*>(&la[m * 192 + ((t ^ (m & 7)) << 3)]);
            }
            #pragma unroll
            for (int ni = 0; ni < 2; ++ni) {
                const int nn = nloc[ni];
                bfr[ni] = *reinterpret_cast<const short8*>(&Bs[nn * 192 + ((t ^ (nn & 7)) << 3)]);
            }
            #pragma unroll
            for (int mi = 0; mi < 2; ++mi)
                #pragma unroll
                for (int ni = 0; ni < 2; ++ni)
                    acc[mi][ni] = __builtin_amdgcn_mfma_f32_16x16x32_bf16(
                        af[mi], bfr[ni], acc[mi][ni], 0, 0, 0);
        }

        // epilogue: direct stores. C/D: col = lane&15, row = (lane>>4)*4 + j
        const int m0   = mt * 64;
        const int rowb = m0 + wm * 32 + (lane >> 4) * 4;
        const int colb = col0 + wn * 32 + (lane & 15);
        #pragma unroll
        for (int mi = 0; mi < 2; ++mi) {
            #pragma unroll
            for (int ni = 0; ni < 2; ++ni) {
                const int c = colb + ni * 16;
                #pragma unroll
                for (int j = 0; j < 4; ++j) {
                    const int row = rowb + mi * 16 + j;
                    float v = acc[mi][ni][j];
                    if constexpr (EPI == 0) {
                        if (isZ) v = 4.0f * silu_f(v);
                    } else {
                        v = silu_f(v + bias[n0 + (c - col0)]);
                    }
                    dst[(size_t)row * stride + c] = __float2bfloat16(v);
                }
            }
        }

        __syncthreads();   // drain next-stage loads; protect buf reuse
        cur ^= 1;
    }
}

// ---------------------------------------------------------------------------
// Loop GEMM (K=384/768): BM=128, BN=64, BK=64. 4 waves 2x2; wave 64x32.
// 1D grid + XCD-bijective swizzle (y%8 == bid%8).
// EPI 1: +residF(fp32) -> outB bf16 only                              [G3]
// EPI 3: v + bias + bf2f(residB) -> outF fp32                         [G5]
// ---------------------------------------------------------------------------
template <int EPI>
__launch_bounds__(256, 4)
__global__ void gemm_mfma(const bf16* __restrict__ A, const bf16* __restrict__ BT,
                          const float* __restrict__ bias,
                          const float* __restrict__ residF,
                          const bf16* __restrict__ residB,
                          float* __restrict__ outF, bf16* __restrict__ outB,
                          int M, int N, int K, int NX)
{
    __shared__ bf16 As[128 * 64];
    __shared__ bf16 Bs[64 * 64];

    const int bid = blockIdx.x;
    const int c8  = bid & 7;
    const int kq  = bid >> 3;
    const int bx  = kq % NX;
    const int by  = (kq / NX) * 8 + c8;
    const int m0  = by * 128;
    const int n0  = bx * 64;

    const int tid  = threadIdx.x;
    const int lane = tid & 63;
    const int wv   = tid >> 6;
    const int wm   = wv >> 1;
    const int wn   = wv & 1;

    const int srow  = lane >> 3;
    const int sslot = lane & 7;

    f32x4 acc[4][2] = {};

    for (int k0 = 0; k0 < K; k0 += 64) {
        #pragma unroll
        for (int i = 0; i < 4; ++i) {
            const int rb = wv * 32 + i * 8;
            const int r  = rb + srow;
            gload_lds16(A + (size_t)(m0 + r) * K + k0 + ((sslot ^ (r & 7)) << 3),
                        &As[rb * 64]);
        }
        #pragma unroll
        for (int i = 0; i < 2; ++i) {
            const int rb = wv * 16 + i * 8;
            const int r  = rb + srow;
            gload_lds16(BT + (size_t)(n0 + r) * K + k0 + ((sslot ^ (r & 7)) << 3),
                        &Bs[rb * 64]);
        }
        __syncthreads();

        #pragma unroll
        for (int kk = 0; kk < 2; ++kk) {
            const int t = kk * 4 + (lane >> 4);
            short8 af[4], bfr[2];
            #pragma unroll
            for (int mi = 0; mi < 4; ++mi) {
                const int m = wm * 64 + mi * 16 + (lane & 15);
                af[mi] = *reinterpret_cast<const short8*>(&As[m * 64 + ((t ^ (m & 7)) << 3)]);
            }
            #pragma unroll
            for (int ni = 0; ni < 2; ++ni) {
                const int n = wn * 32 + ni * 16 + (lane & 15);
                bfr[ni] = *reinterpret_cast<const short8*>(&Bs[n * 64 + ((t ^ (n & 7)) << 3)]);
            }
            #pragma unroll
            for (int mi = 0; mi < 4; ++mi)
                #pragma unroll
                for (int ni = 0; ni < 2; ++ni)
                    acc[mi][ni] = __builtin_amdgcn_mfma_f32_16x16x32_bf16(
                        af[mi], bfr[ni], acc[mi][ni], 0, 0, 0);
        }
        __syncthreads();
    }

    const int colb = n0 + wn * 32 + (lane & 15);
    const int rowb = m0 + wm * 64 + (lane >> 4) * 4;
    #pragma unroll
    for (int mi = 0; mi < 4; ++mi) {
        #pragma unroll
        for (int ni = 0; ni < 2; ++ni) {
            const int c = colb + ni * 16;
            #pragma unroll
            for (int j = 0; j < 4; ++j) {
                const int row = rowb + mi * 16 + j;
                const size_t off = (size_t)row * N + c;
                const float v = acc[mi][ni][j];
                if constexpr (EPI == 1) {
                    outB[off] = __float2bfloat16(v + residF[off]);
                } else {
                    outF[off] = v + bias[c] + bf2f(*(const short*)&residB[off]);
                }
            }
        }
    }
}

// ---------------------------------------------------------------------------
// Depthwise 3x3 conv + bias + silu, gated. Dense streams:
// x1 [M,384] bf16, sz [M,384] bf16 (= 4*silu(z)). Item f = m*48 + cg.
// y[m,c] = silu(conv(x1)+b) * sz.  Grid: 6144 blocks x 256 thr, XCD-swizzled.
// ---------------------------------------------------------------------------
__launch_bounds__(256)
__global__ void dwconv_gate_v6(const bf16* __restrict__ x1, const bf16* __restrict__ sz,
                               const float* __restrict__ wT, const float* __restrict__ conv_b,
                               bf16* __restrict__ y)
{
    const int bid = blockIdx.x;
    const int swz = (bid & 7) * ((int)gridDim.x >> 3) + (bid >> 3);   // bijective (6144 % 8 == 0)
    const int f   = swz * 256 + threadIdx.x;
    const int m   = f / 48;
    const int cg  = f - m * 48;
    const int c0  = cg * 8;
    const int h   = (m >> 6) & 63;
    const int w   = m & 63;

    float acc[8];
    {
        const f32x4 ba = *reinterpret_cast<const f32x4*>(&conv_b[c0]);
        const f32x4 bb = *reinterpret_cast<const f32x4*>(&conv_b[c0 + 4]);
        acc[0] = ba[0]; acc[1] = ba[1]; acc[2] = ba[2]; acc[3] = ba[3];
        acc[4] = bb[0]; acc[5] = bb[1]; acc[6] = bb[2]; acc[7] = bb[3];
    }

    #pragma unroll
    for (int r = 0; r < 3; ++r) {
        const int hh = h + r - 1;
        if (hh < 0 || hh >= HDIM) continue;
        #pragma unroll
        for (int dw = 0; dw < 3; ++dw) {
            const int ww = w + dw - 1;
            if (ww < 0 || ww >= WDIM) continue;
            const int mm  = m + (r - 1) * WDIM + (dw - 1);
            const int tap = r * 3 + dw;
            const short8 t = *reinterpret_cast<const short8*>(&x1[(size_t)mm * CIDIM + c0]);
            const f32x4 wa = *reinterpret_cast<const f32x4*>(&wT[tap * CIDIM + c0]);
            const f32x4 wb = *reinterpret_cast<const f32x4*>(&wT[tap * CIDIM + c0 + 4]);
            acc[0] += bf2f(t[0]) * wa[0]; acc[1] += bf2f(t[1]) * wa[1];
            acc[2] += bf2f(t[2]) * wa[2]; acc[3] += bf2f(t[3]) * wa[3];
            acc[4] += bf2f(t[4]) * wb[0]; acc[5] += bf2f(t[5]) * wb[1];
            acc[6] += bf2f(t[6]) * wb[2]; acc[7] += bf2f(t[7]) * wb[3];
        }
    }

    const short8 g = *reinterpret_cast<const short8*>(&sz[(size_t)m * CIDIM + c0]);
    bf16 tmp[8];
    #pragma unroll
    for (int j = 0; j < 8; ++j)
        tmp[j] = __float2bfloat16(silu_f(acc[j]) * bf2f(g[j]));
    *reinterpret_cast<short8*>(&y[(size_t)m * CIDIM + c0]) =
        *reinterpret_cast<const short8*>(tmp);
}

// ---------------------------------------------------------------------------
// ALL preprocessing in ONE launch: x fp32->bf16 (4/thread) + 4 weight
// transposes to bf16 [N,K] + conv_w transpose, flat-index dispatched.
// ---------------------------------------------------------------------------
#define SZ_WIN  (192 * 768)
#define SZ_WOUT (384 * 192)
#define SZ_WM1  (192 * 768)
#define SZ_WM2  (768 * 192)
#define SZ_CW   (CIDIM * 9)
#define XCVT    (MTOK * CDIM / 4)
#define SZ_ALL  (XCVT + SZ_WIN + SZ_WOUT + SZ_WM1 + SZ_WM2 + SZ_CW)

__launch_bounds__(256)
__global__ void prep_all(const float* __restrict__ x, const float* __restrict__ Win,
                         const float* __restrict__ Wout, const float* __restrict__ Wm1,
                         const float* __restrict__ Wm2, const float* __restrict__ convw,
                         bf16* __restrict__ xb, bf16* __restrict__ WinT,
                         bf16* __restrict__ WoutT, bf16* __restrict__ Wm1T,
                         bf16* __restrict__ Wm2T, float* __restrict__ wTc)
{
    int idx = blockIdx.x * 256 + threadIdx.x;
    if (idx < XCVT) {
        const int i = idx * 4;
        const float4 v = *reinterpret_cast<const float4*>(&x[i]);
        xb[i + 0] = __float2bfloat16(v.x);
        xb[i + 1] = __float2bfloat16(v.y);
        xb[i + 2] = __float2bfloat16(v.z);
        xb[i + 3] = __float2bfloat16(v.w);
        return;
    }
    idx -= XCVT;
    if (idx < SZ_WIN) {
        const int r = idx / 768, c = idx % 768;
        WinT[(size_t)c * 192 + r] = __float2bfloat16(Win[idx]);
        return;
    }
    idx -= SZ_WIN;
    if (idx < SZ_WOUT) {
        const int r = idx / 192, c = idx % 192;
        WoutT[(size_t)c * 384 + r] = __float2bfloat16(Wout[idx]);
        return;
    }
    idx -= SZ_WOUT;
    if (idx < SZ_WM1) {
        const int r = idx / 768, c = idx % 768;
        Wm1T[(size_t)c * 192 + r] = __float2bfloat16(Wm1[idx]);
        return;
    }
    idx -= SZ_WM1;
    if (idx < SZ_WM2) {
        const int r = idx / 192, c = idx % 192;
        Wm2T[(size_t)c * 768 + r] = __float2bfloat16(Wm2[idx]);
        return;
    }
    idx -= SZ_WM2;
    if (idx < SZ_CW) {
        const int ci = idx / 9, t = idx % 9;
        wTc[t * CIDIM + ci] = convw[idx];
    }
}

// ---------------------------------------------------------------------------
extern "C" void kernel_launch(void* const* d_in, const int* in_sizes, int n_in,
                              void* d_out, int out_size, void* d_ws, size_t ws_size,
                              hipStream_t stream)
{
    const float* x      = (const float*)d_in[0];
    const float* Win    = (const float*)d_in[1];
    const float* conv_w = (const float*)d_in[2];
    const float* conv_b = (const float*)d_in[3];
    const float* Wout   = (const float*)d_in[4];
    const float* Wm1    = (const float*)d_in[5];
    const float* bm1    = (const float*)d_in[6];
    const float* Wm2    = (const float*)d_in[7];
    const float* bm2    = (const float*)d_in[8];
    float* out = (float*)d_out;

    char* ws = (char*)d_ws;
    size_t o = 0;
    bf16*  xb    = (bf16*)(ws + o); o += (size_t)MTOK * CDIM * 2;
    bf16*  WinT  = (bf16*)(ws + o); o += (size_t)768 * 192 * 2;
    bf16*  WoutT = (bf16*)(ws + o); o += (size_t)192 * 384 * 2;
    bf16*  Wm1T  = (bf16*)(ws + o); o += (size_t)768 * 192 * 2;
    bf16*  Wm2T  = (bf16*)(ws + o); o += (size_t)192 * 768 * 2;
    float* wTc   = (float*)(ws + o); o += (size_t)9 * CIDIM * 4;
    bf16*  ws_x1 = (bf16*)(ws + o); o += (size_t)MTOK * CIDIM * 2;   // dense x1 [M,384]
    bf16*  ws_sz = (bf16*)(ws + o); o += (size_t)MTOK * CIDIM * 2;   // dense 4*silu(z)
    bf16*  ws_y  = (bf16*)(ws + o); o += (size_t)MTOK * CIDIM * 2;
    bf16*  ws_ob = (bf16*)(ws + o); o += (size_t)MTOK * CDIM * 2;    // out bf16 [M,192]
    bf16*  ws_h  = ws_x1;   // GEMM4 output [M,768] reuses x1+sz region (dead by then)

    // 0) all conversions/transposes in one launch
    prep_all<<<dim3((SZ_ALL + 255) / 256), dim3(256), 0, stream>>>(
        x, Win, Wout, Wm1, Wm2, conv_w, xb, WinT, WoutT, Wm1T, Wm2T, wTc);

    // 1) xz = x @ Win  [M,768], K=192 -> split dense x1 / sz(=4*silu(z))
    //    persistent 2-phase, B resident, A double-buffered
    gemm_k192_p<0><<<dim3(12 * NSTRIPE), dim3(256), 0, stream>>>(
        xb, WinT, nullptr, ws_x1, ws_sz);

    // 2) y = silu(dwconv(x1)+b) * sz -> bf16
    dwconv_gate_v6<<<dim3(MTOK * 48 / 256), dim3(256), 0, stream>>>(
        ws_x1, ws_sz, wTc, conv_b, ws_y);

    // 3) out = x + y @ Wout   [M,192], K=384 -> bf16 ob ONLY
    gemm_mfma<1><<<dim3(3 * 256), dim3(256), 0, stream>>>(
        ws_y, WoutT, nullptr, x, nullptr, nullptr, ws_ob, MTOK, CDIM, CIDIM, 3);

    // 4) h = silu(out @ Wm1 + bm1)   [M,768], K=192 -> bf16 (persistent)
    gemm_k192_p<2><<<dim3(12 * NSTRIPE), dim3(256), 0, stream>>>(
        ws_ob, Wm1T, bm1, ws_h, nullptr);

    // 5) final = bf16(out) + h @ Wm2 + bm2   [M,192], K=768 -> fp32
    gemm_mfma<3><<<dim3(3 * 256), dim3(256), 0, stream>>>(
        ws_h, Wm2T, bm2, nullptr, ws_ob, out, nullptr, MTOK, CDIM, 768, 3);
}